// Round 1
// baseline (110.216 us; speedup 1.0000x reference)
//
#include <hip/hip_runtime.h>
#include <math.h>

#define NQ_     14
#define DIM_    16384
#define NB      256
#define NLAYERS 3
#define NPAIR   13
#define NT      1024
#define APT     (DIM_ / NT)   // 16 amplitudes per thread

__device__ __forceinline__ float2 cmul(float2 a, float2 b) {
    return make_float2(a.x * b.x - a.y * b.y, a.x * b.y + a.y * b.x);
}

__global__ __launch_bounds__(NT, 1) void pqc_kernel(
    const float* __restrict__ x,     // (256, 28)
    const float* __restrict__ psq,   // (3, 2, 14, 3)
    const float* __restrict__ p2q,   // (3, 196)
    const float* __restrict__ penc,  // (3, 196)
    const float* __restrict__ pcl,   // (14,)
    float* __restrict__ out)         // (256,)
{
    __shared__ float2 s_amp[DIM_];           // 128 KiB state
    __shared__ float2 s_U[4][NQ_][4];        // merged gate matrices
    __shared__ float2 s_C0[NLAYERS][128];    // diag cis tables (low 7 xor-bits)
    __shared__ float2 s_C1[NLAYERS][64];     // diag cis tables (high 6 xor-bits, -S/2 folded)
    __shared__ float  s_theta[NLAYERS][NPAIR];
    __shared__ float  s_WL[128];             // Z-measure weight, low 7 bits
    __shared__ float  s_WH[128];             // Z-measure weight, high 7 bits (Cz folded)
    __shared__ float  s_red[16];

    const int n = blockIdx.x;
    const int tid = threadIdx.x;

    // ---------------- phase 1: state init + theta + WZ tables + gate matrices ----------------
    #pragma unroll
    for (int r = 0; r < APT; ++r) {
        int k = tid + r * NT;
        s_amp[k] = make_float2(k == 0 ? 1.0f : 0.0f, 0.0f);
    }

    if (tid < NLAYERS * NPAIR) {
        // theta[l][p] = p2q[l, 15p+1] + penc[l, 15p+1] * feat[p]
        int l = tid / NPAIR, p = tid - l * NPAIR;
        const float* xr = x + n * 28;
        float feat = xr[2 * p] * xr[2 * p + 2] + xr[2 * p + 1] * xr[2 * p + 3];
        int pf = 15 * p + 1;
        s_theta[l][p] = p2q[l * 196 + pf] + penc[l * 196 + pf] * feat;
    } else if (tid >= 64 && tid < 192) {
        // WL[i] = sum_{b=0..6} pcl[13-b] * bit(i,b)
        int i = tid - 64;
        float v = 0.0f;
        #pragma unroll
        for (int b = 0; b < 7; ++b)
            if ((i >> b) & 1) v += pcl[13 - b];
        s_WL[i] = v;
    } else if (tid >= 192 && tid < 320) {
        // WH[j] = Cz - 2 * sum_{b=7..13} pcl[13-b] * bit(j,b-7)
        int j = tid - 192;
        float cz = 0.0f;
        #pragma unroll
        for (int q = 0; q < NQ_; ++q) cz += pcl[q];
        float v = 0.0f;
        #pragma unroll
        for (int b = 7; b < 14; ++b)
            if ((j >> (b - 7)) & 1) v += pcl[13 - b];
        s_WH[j] = cz - 2.0f * v;
    } else if (tid >= 384 && tid < 384 + 4 * NQ_) {
        // gate matrices: set0 = U0(L0); set1 = U0(L1)*U1(L0); set2 = U0(L2)*U1(L1); set3 = U1(L2)
        int j = tid - 384;
        int set = j / NQ_;
        int q = j - set * NQ_;
        auto build = [&](int l, int s, float2 Uo[4]) {
            const float* a = psq + ((l * 2 + s) * NQ_ + q) * 3;
            float phi = a[0], th = a[1], om = a[2];
            float sh, ch; sincosf(0.5f * th, &sh, &ch);
            float sa, ca; sincosf(0.5f * (phi + om), &sa, &ca);
            float sb, cb; sincosf(0.5f * (phi - om), &sb, &cb);
            Uo[0] = make_float2( ch * ca, -ch * sa);   // ep*c
            Uo[1] = make_float2(-sh * cb, -sh * sb);   // -conj(em)*s
            Uo[2] = make_float2( sh * cb, -sh * sb);   // em*s
            Uo[3] = make_float2( ch * ca,  ch * sa);   // conj(ep)*c
        };
        float2 M[4];
        if (set == 0) {
            build(0, 0, M);
        } else if (set == 3) {
            build(2, 1, M);
        } else {
            float2 A[4], Bm[4];
            build(set, 0, A);        // applied second
            build(set - 1, 1, Bm);   // applied first
            M[0].x = A[0].x*Bm[0].x - A[0].y*Bm[0].y + A[1].x*Bm[2].x - A[1].y*Bm[2].y;
            M[0].y = A[0].x*Bm[0].y + A[0].y*Bm[0].x + A[1].x*Bm[2].y + A[1].y*Bm[2].x;
            M[1].x = A[0].x*Bm[1].x - A[0].y*Bm[1].y + A[1].x*Bm[3].x - A[1].y*Bm[3].y;
            M[1].y = A[0].x*Bm[1].y + A[0].y*Bm[1].x + A[1].x*Bm[3].y + A[1].y*Bm[3].x;
            M[2].x = A[2].x*Bm[0].x - A[2].y*Bm[0].y + A[3].x*Bm[2].x - A[3].y*Bm[2].y;
            M[2].y = A[2].x*Bm[0].y + A[2].y*Bm[0].x + A[3].x*Bm[2].y + A[3].y*Bm[2].x;
            M[3].x = A[2].x*Bm[1].x - A[2].y*Bm[1].y + A[3].x*Bm[3].x - A[3].y*Bm[3].y;
            M[3].y = A[2].x*Bm[1].y + A[2].y*Bm[1].x + A[3].x*Bm[3].y + A[3].y*Bm[3].x;
        }
        #pragma unroll
        for (int e = 0; e < 4; ++e) s_U[set][q][e] = M[e];
    }
    __syncthreads();

    // ---------------- phase 2: diag cis tables (need theta) ----------------
    if (tid < NLAYERS * 128) {
        int l = tid >> 7, i = tid & 127;
        float v = 0.0f;
        #pragma unroll
        for (int b = 0; b < 7; ++b)
            if ((i >> b) & 1) v += s_theta[l][12 - b];
        float sn, cs; sincosf(v, &sn, &cs);
        s_C0[l][i] = make_float2(cs, sn);
    } else if (tid < NLAYERS * 128 + NLAYERS * 64) {
        int j = tid - NLAYERS * 128;
        int l = j >> 6, h = j & 63;
        float S = 0.0f;
        #pragma unroll
        for (int p = 0; p < NPAIR; ++p) S += s_theta[l][p];
        float v = -0.5f * S;
        #pragma unroll
        for (int b = 7; b < 13; ++b)
            if ((h >> (b - 7)) & 1) v += s_theta[l][12 - b];
        float sn, cs; sincosf(v, &sn, &cs);
        s_C1[l][h] = make_float2(cs, sn);
    }
    __syncthreads();

    // ---------------- circuit ----------------
    auto gate2 = [&](float2 a0, float2 a1, float2& o0, float2& o1,
                     float2 u00, float2 u01, float2 u10, float2 u11) {
        o0.x = u00.x*a0.x - u00.y*a0.y + u01.x*a1.x - u01.y*a1.y;
        o0.y = u00.x*a0.y + u00.y*a0.x + u01.x*a1.y + u01.y*a1.x;
        o1.x = u10.x*a0.x - u10.y*a0.y + u11.x*a1.x - u11.y*a1.y;
        o1.y = u10.x*a0.y + u10.y*a0.x + u11.x*a1.y + u11.y*a1.x;
    };

    for (int set = 0; set < 4; ++set) {
        for (int bp = 0; bp < NQ_; ++bp) {
            int q = NQ_ - 1 - bp;  // qubit index for this bit position
            float2 u00 = s_U[set][q][0], u01 = s_U[set][q][1];
            float2 u10 = s_U[set][q][2], u11 = s_U[set][q][3];
            if (bp < 2) {
                // 4 consecutive amplitudes per iteration: contiguous LDS, no bank conflicts
                #pragma unroll
                for (int r = 0; r < 4; ++r) {
                    int base = (tid + r * NT) << 2;
                    float2 a0 = s_amp[base + 0], a1 = s_amp[base + 1];
                    float2 a2 = s_amp[base + 2], a3 = s_amp[base + 3];
                    float2 b0, b1, b2, b3;
                    if (bp == 0) {
                        gate2(a0, a1, b0, b1, u00, u01, u10, u11);
                        gate2(a2, a3, b2, b3, u00, u01, u10, u11);
                    } else {
                        gate2(a0, a2, b0, b2, u00, u01, u10, u11);
                        gate2(a1, a3, b1, b3, u00, u01, u10, u11);
                    }
                    s_amp[base + 0] = b0; s_amp[base + 1] = b1;
                    s_amp[base + 2] = b2; s_amp[base + 3] = b3;
                }
            } else {
                int stride = 1 << bp;
                #pragma unroll
                for (int r = 0; r < 8; ++r) {
                    int t = tid + r * NT;
                    int idx0 = ((t >> bp) << (bp + 1)) | (t & (stride - 1));
                    int idx1 = idx0 + stride;
                    float2 a0 = s_amp[idx0], a1 = s_amp[idx1];
                    float2 b0, b1;
                    gate2(a0, a1, b0, b1, u00, u01, u10, u11);
                    s_amp[idx0] = b0; s_amp[idx1] = b1;
                }
            }
            __syncthreads();
        }
        if (set < NLAYERS) {
            // ZZ diagonal: amp[k] *= C0[m&127] * C1[(m>>7)&63], m = k ^ (k>>1)
            #pragma unroll
            for (int r = 0; r < APT; ++r) {
                int k = tid + r * NT;
                int m = k ^ (k >> 1);
                float2 ph = cmul(s_C0[set][m & 127], s_C1[set][(m >> 7) & 63]);
                s_amp[k] = cmul(s_amp[k], ph);
            }
            __syncthreads();
        }
    }

    // ---------------- measurements ----------------
    float acc = 0.0f;
    // Z part: sum_k |amp|^2 * (WH[k>>7] - 2*WL[k&127])
    #pragma unroll
    for (int r = 0; r < APT; ++r) {
        int k = tid + r * NT;
        float2 a = s_amp[k];
        float pr = a.x * a.x + a.y * a.y;
        acc += pr * (s_WH[k >> 7] - 2.0f * s_WL[k & 127]);
    }
    // X part: coeff for qubit q = 13-bp is pcl[bp]; expX = 2*sum Re(conj(a0)*a1)
    for (int bp = 0; bp < NQ_; ++bp) {
        float cx = 2.0f * pcl[bp];
        int stride = 1 << bp;
        float xs = 0.0f;
        #pragma unroll
        for (int r = 0; r < 8; ++r) {
            int t = tid + r * NT;
            int idx0 = ((t >> bp) << (bp + 1)) | (t & (stride - 1));
            float2 a0 = s_amp[idx0], a1 = s_amp[idx0 + stride];
            xs += a0.x * a1.x + a0.y * a1.y;
        }
        acc += cx * xs;
    }

    // block reduction
    #pragma unroll
    for (int off = 32; off > 0; off >>= 1)
        acc += __shfl_down(acc, off);
    if ((tid & 63) == 0) s_red[tid >> 6] = acc;
    __syncthreads();
    if (tid == 0) {
        float s = 0.0f;
        #pragma unroll
        for (int w = 0; w < 16; ++w) s += s_red[w];
        out[n] = s;
    }
}

extern "C" void kernel_launch(void* const* d_in, const int* in_sizes, int n_in,
                              void* d_out, int out_size, void* d_ws, size_t ws_size,
                              hipStream_t stream) {
    const float* x    = (const float*)d_in[0];
    const float* psq  = (const float*)d_in[1];
    const float* p2q  = (const float*)d_in[2];
    const float* penc = (const float*)d_in[3];
    const float* pcl  = (const float*)d_in[4];
    float* out = (float*)d_out;
    pqc_kernel<<<NB, NT, 0, stream>>>(x, psq, p2q, penc, pcl, out);
}

// Round 4
// 45.642 us; speedup vs baseline: 2.4148x; 2.4148x over previous
//
#include <hip/hip_runtime.h>
#include <math.h>

#define NQ_     14
#define DIM_    16384
#define NB      256
#define NLAYERS 3
#define NPAIR   13
#define NT      1024

// LDS swizzle: XOR bits 1-3 of the float2 index with bits 4-6.
// Verified conflict-free for all four pass layouts (b128 for A/D, b64 for B/C).
#define SW(k) ((k) ^ ((((k) >> 4) & 7) << 1))

__device__ __forceinline__ float2 cmul(float2 a, float2 b) {
    return make_float2(a.x*b.x - a.y*b.y, a.x*b.y + a.y*b.x);
}

__device__ __forceinline__ void g2(float2& a0, float2& a1,
        float2 u00, float2 u01, float2 u10, float2 u11) {
    float2 b0, b1;
    b0.x = u00.x*a0.x - u00.y*a0.y + u01.x*a1.x - u01.y*a1.y;
    b0.y = u00.x*a0.y + u00.y*a0.x + u01.x*a1.y + u01.y*a1.x;
    b1.x = u10.x*a0.x - u10.y*a0.y + u11.x*a1.x - u11.y*a1.y;
    b1.y = u10.x*a0.y + u10.y*a0.x + u11.x*a1.y + u11.y*a1.x;
    a0 = b0; a1 = b1;
}

// apply a 2x2 gate across register bit RB of a[16]; U = LDS ptr to 4 float2
#define GATE_BIT(RB, Uptr) do { \
    float2 u00 = (Uptr)[0], u01 = (Uptr)[1], u10 = (Uptr)[2], u11 = (Uptr)[3]; \
    _Pragma("unroll") \
    for (int j = 0; j < 16; ++j) \
        if (!((j >> (RB)) & 1)) g2(a[j], a[j | (1 << (RB))], u00, u01, u10, u11); \
} while (0)

__global__ __launch_bounds__(NT, 1) void pqc_kernel(
    const float* __restrict__ x,     // (256, 28)
    const float* __restrict__ psq,   // (3, 2, 14, 3)
    const float* __restrict__ p2q,   // (3, 196)
    const float* __restrict__ penc,  // (3, 196)
    const float* __restrict__ pcl,   // (14,)
    float* __restrict__ out)         // (256,)
{
    __shared__ __align__(16) float2 s_amp[DIM_];   // 128 KiB state
    __shared__ float2 s_U[4][NQ_][4];              // merged gate sets
    __shared__ float2 s_C0[NLAYERS][128];          // diag cis (low 7 xor-bits)
    __shared__ float2 s_C1[NLAYERS][64];           // diag cis (high 6 xor-bits, -S/2 folded)
    __shared__ float  s_theta[NLAYERS][NPAIR];
    __shared__ float  s_red[16];

    const int n = blockIdx.x;
    const int t = threadIdx.x;

    // ---------- phase 1: theta + merged gate matrices ----------
    if (t < NLAYERS * NPAIR) {
        int l = t / NPAIR, p = t - l * NPAIR;
        const float* xr = x + n * 28;
        float feat = xr[2*p] * xr[2*p+2] + xr[2*p+1] * xr[2*p+3];
        int pf = 15 * p + 1;
        s_theta[l][p] = p2q[l*196 + pf] + penc[l*196 + pf] * feat;
    } else if (t >= 64 && t < 64 + 4 * NQ_) {
        // set0 = U0(L0); set1 = U0(L1)*U1(L0); set2 = U0(L2)*U1(L1); set3 = U1(L2)
        int j = t - 64;
        int set = j / NQ_;
        int q = j - set * NQ_;
        auto build = [&](int l, int s, float2 Uo[4]) {
            const float* a = psq + ((l * 2 + s) * NQ_ + q) * 3;
            float phi = a[0], th = a[1], om = a[2];
            float sh, ch; sincosf(0.5f * th, &sh, &ch);
            float sa, ca; sincosf(0.5f * (phi + om), &sa, &ca);
            float sb, cb; sincosf(0.5f * (phi - om), &sb, &cb);
            Uo[0] = make_float2( ch * ca, -ch * sa);
            Uo[1] = make_float2(-sh * cb, -sh * sb);
            Uo[2] = make_float2( sh * cb, -sh * sb);
            Uo[3] = make_float2( ch * ca,  ch * sa);
        };
        float2 M[4];
        if (set == 0) {
            build(0, 0, M);
        } else if (set == 3) {
            build(2, 1, M);
        } else {
            float2 A[4], Bm[4];
            build(set, 0, A);        // second
            build(set - 1, 1, Bm);   // first
            M[0].x = A[0].x*Bm[0].x - A[0].y*Bm[0].y + A[1].x*Bm[2].x - A[1].y*Bm[2].y;
            M[0].y = A[0].x*Bm[0].y + A[0].y*Bm[0].x + A[1].x*Bm[2].y + A[1].y*Bm[2].x;
            M[1].x = A[0].x*Bm[1].x - A[0].y*Bm[1].y + A[1].x*Bm[3].x - A[1].y*Bm[3].y;
            M[1].y = A[0].x*Bm[1].y + A[0].y*Bm[1].x + A[1].x*Bm[3].y + A[1].y*Bm[3].x;
            M[2].x = A[2].x*Bm[0].x - A[2].y*Bm[0].y + A[3].x*Bm[2].x - A[3].y*Bm[2].y;
            M[2].y = A[2].x*Bm[0].y + A[2].y*Bm[0].x + A[3].x*Bm[2].y + A[3].y*Bm[2].x;
            M[3].x = A[2].x*Bm[1].x - A[2].y*Bm[1].y + A[3].x*Bm[3].x - A[3].y*Bm[3].y;
            M[3].y = A[2].x*Bm[1].y + A[2].y*Bm[1].x + A[3].x*Bm[3].y + A[3].y*Bm[3].x;
        }
        #pragma unroll
        for (int e = 0; e < 4; ++e) s_U[set][q][e] = M[e];
    }
    __syncthreads();

    // ---------- phase 2: diag cis tables ----------
    if (t < NLAYERS * 128) {
        int l = t >> 7, i = t & 127;
        float v = 0.0f;
        #pragma unroll
        for (int b = 0; b < 7; ++b)
            if ((i >> b) & 1) v += s_theta[l][12 - b];
        float sn, cs; sincosf(v, &sn, &cs);
        s_C0[l][i] = make_float2(cs, sn);
    } else if (t < NLAYERS * 128 + NLAYERS * 64) {
        int j = t - NLAYERS * 128;
        int l = j >> 6, h = j & 63;
        float S = 0.0f;
        #pragma unroll
        for (int p = 0; p < NPAIR; ++p) S += s_theta[l][p];
        float v = -0.5f * S;
        #pragma unroll
        for (int b = 7; b < 13; ++b)
            if ((h >> (b - 7)) & 1) v += s_theta[l][12 - b];
        float sn, cs; sincosf(v, &sn, &cs);
        s_C1[l][h] = make_float2(cs, sn);
    }
    __syncthreads();

    float2 a[16];
    float acc = 0.0f;

    // ---- load/store macros: layouts A(bits0-3), B(4-7), C(8-11), D(12,13,0,1) ----
#define LOAD_A() do { _Pragma("unroll") for (int c = 0; c < 8; ++c) { \
        int p = SW((t << 4) | (2*c)); \
        float4 v = *(const float4*)&s_amp[p]; \
        a[2*c] = make_float2(v.x, v.y); a[2*c+1] = make_float2(v.z, v.w); } } while (0)
#define STORE_A() do { _Pragma("unroll") for (int c = 0; c < 8; ++c) { \
        int p = SW((t << 4) | (2*c)); \
        *(float4*)&s_amp[p] = make_float4(a[2*c].x, a[2*c].y, a[2*c+1].x, a[2*c+1].y); } } while (0)
#define LOAD_B() do { int bb = ((t >> 4) << 8) | (t & 15); _Pragma("unroll") \
        for (int j = 0; j < 16; ++j) a[j] = s_amp[SW(bb | (j << 4))]; } while (0)
#define STORE_B() do { int bb = ((t >> 4) << 8) | (t & 15); _Pragma("unroll") \
        for (int j = 0; j < 16; ++j) s_amp[SW(bb | (j << 4))] = a[j]; } while (0)
#define LOAD_C() do { int bc = ((t >> 8) << 12) | (t & 255); _Pragma("unroll") \
        for (int j = 0; j < 16; ++j) a[j] = s_amp[SW(bc | (j << 8))]; } while (0)
#define STORE_C() do { int bc = ((t >> 8) << 12) | (t & 255); _Pragma("unroll") \
        for (int j = 0; j < 16; ++j) s_amp[SW(bc | (j << 8))] = a[j]; } while (0)
#define LOAD_D() do { _Pragma("unroll") for (int jh = 0; jh < 4; ++jh) \
        _Pragma("unroll") for (int c = 0; c < 2; ++c) { \
        int p = SW((jh << 12) | (t << 2) | (2*c)); \
        float4 v = *(const float4*)&s_amp[p]; \
        a[jh*4+2*c] = make_float2(v.x, v.y); a[jh*4+2*c+1] = make_float2(v.z, v.w); } } while (0)
#define STORE_D() do { _Pragma("unroll") for (int jh = 0; jh < 4; ++jh) \
        _Pragma("unroll") for (int c = 0; c < 2; ++c) { \
        int p = SW((jh << 12) | (t << 2) | (2*c)); \
        *(float4*)&s_amp[p] = make_float4(a[jh*4+2*c].x, a[jh*4+2*c].y, a[jh*4+2*c+1].x, a[jh*4+2*c+1].y); } } while (0)

#define DIAG(l, KEXPR) do { _Pragma("unroll") for (int j = 0; j < 16; ++j) { \
        int k = (KEXPR); int m = k ^ (k >> 1); \
        float2 ph = cmul(s_C0[l][m & 127], s_C1[l][(m >> 7) & 63]); \
        a[j] = cmul(a[j], ph); } } while (0)

    // measurement for 4 register bits mapped to state bits B0..B0+3
#define EPI4(B0) do { float pr[16]; \
        _Pragma("unroll") for (int j = 0; j < 16; ++j) pr[j] = a[j].x*a[j].x + a[j].y*a[j].y; \
        _Pragma("unroll") for (int rb = 0; rb < 4; ++rb) { \
            int bp = (B0) + rb; float xs = 0.f, zs = 0.f; \
            _Pragma("unroll") for (int j = 0; j < 16; ++j) { \
                if (!((j >> rb) & 1)) { int j1 = j | (1 << rb); xs += a[j].x*a[j1].x + a[j].y*a[j1].y; } \
                zs += ((j >> rb) & 1) ? -pr[j] : pr[j]; } \
            acc += 2.0f * pcl[bp] * xs + pcl[13 - bp] * zs; } } while (0)

    // ---- P1 (layout D): analytic set0 product state, diag0, set1 gates bits12,13 ----
    {
        float2 F = make_float2(1.f, 0.f);
        #pragma unroll
        for (int bp = 2; bp < 12; ++bp) {
            int b = (t >> (bp - 2)) & 1;
            float2 f = s_U[0][13 - bp][b ? 2 : 0];   // column-0 of qubit 13-bp
            F = cmul(F, f);
        }
        float2 g01[4], g23[4];
        #pragma unroll
        for (int j1 = 0; j1 < 2; ++j1)
            #pragma unroll
            for (int j0 = 0; j0 < 2; ++j0)
                g01[(j1 << 1) | j0] = cmul(s_U[0][13][j0 ? 2 : 0], s_U[0][12][j1 ? 2 : 0]);
        #pragma unroll
        for (int j3 = 0; j3 < 2; ++j3)
            #pragma unroll
            for (int j2 = 0; j2 < 2; ++j2)
                g23[(j3 << 1) | j2] = cmul(s_U[0][1][j2 ? 2 : 0], s_U[0][0][j3 ? 2 : 0]);
        float2 Fg[4];
        #pragma unroll
        for (int jl = 0; jl < 4; ++jl) Fg[jl] = cmul(F, g01[jl]);
        #pragma unroll
        for (int j = 0; j < 16; ++j) a[j] = cmul(Fg[j & 3], g23[j >> 2]);
    }
    DIAG(0, ((j >> 2) << 12) | (t << 2) | (j & 3));
    GATE_BIT(2, s_U[1][1]);   // bit12 -> qubit 1
    GATE_BIT(3, s_U[1][0]);   // bit13 -> qubit 0
    STORE_D(); __syncthreads();

    // ---- P2 (C): set1 bits 8-11 ----
    LOAD_C();
    GATE_BIT(0, s_U[1][5]); GATE_BIT(1, s_U[1][4]);
    GATE_BIT(2, s_U[1][3]); GATE_BIT(3, s_U[1][2]);
    STORE_C(); __syncthreads();

    // ---- P3 (B): set1 bits 4-7 ----
    LOAD_B();
    GATE_BIT(0, s_U[1][9]); GATE_BIT(1, s_U[1][8]);
    GATE_BIT(2, s_U[1][7]); GATE_BIT(3, s_U[1][6]);
    STORE_B(); __syncthreads();

    // ---- P4 (A): set1 bits 0-3, diag1, set2 bits 0-3 ----
    LOAD_A();
    GATE_BIT(0, s_U[1][13]); GATE_BIT(1, s_U[1][12]);
    GATE_BIT(2, s_U[1][11]); GATE_BIT(3, s_U[1][10]);
    DIAG(1, (t << 4) | j);
    GATE_BIT(0, s_U[2][13]); GATE_BIT(1, s_U[2][12]);
    GATE_BIT(2, s_U[2][11]); GATE_BIT(3, s_U[2][10]);
    STORE_A(); __syncthreads();

    // ---- P5 (B): set2 bits 4-7 ----
    LOAD_B();
    GATE_BIT(0, s_U[2][9]); GATE_BIT(1, s_U[2][8]);
    GATE_BIT(2, s_U[2][7]); GATE_BIT(3, s_U[2][6]);
    STORE_B(); __syncthreads();

    // ---- P6 (C): set2 bits 8-11 ----
    LOAD_C();
    GATE_BIT(0, s_U[2][5]); GATE_BIT(1, s_U[2][4]);
    GATE_BIT(2, s_U[2][3]); GATE_BIT(3, s_U[2][2]);
    STORE_C(); __syncthreads();

    // ---- P7 (D): set2 bits 12,13; diag2; set3 bits 12,13; measure bits 12,13 ----
    LOAD_D();
    GATE_BIT(2, s_U[2][1]); GATE_BIT(3, s_U[2][0]);
    DIAG(2, ((j >> 2) << 12) | (t << 2) | (j & 3));
    GATE_BIT(2, s_U[3][1]); GATE_BIT(3, s_U[3][0]);
    {
        float pr[16];
        #pragma unroll
        for (int j = 0; j < 16; ++j) pr[j] = a[j].x*a[j].x + a[j].y*a[j].y;
        #pragma unroll
        for (int rb = 2; rb < 4; ++rb) {
            int bp = 10 + rb; float xs = 0.f, zs = 0.f;
            #pragma unroll
            for (int j = 0; j < 16; ++j) {
                if (!((j >> rb) & 1)) { int j1 = j | (1 << rb); xs += a[j].x*a[j1].x + a[j].y*a[j1].y; }
                zs += ((j >> rb) & 1) ? -pr[j] : pr[j];
            }
            acc += 2.0f * pcl[bp] * xs + pcl[13 - bp] * zs;
        }
    }
    STORE_D(); __syncthreads();

    // ---- P8 (C): set3 bits 8-11 + measure ----
    LOAD_C();
    GATE_BIT(0, s_U[3][5]); GATE_BIT(1, s_U[3][4]);
    GATE_BIT(2, s_U[3][3]); GATE_BIT(3, s_U[3][2]);
    EPI4(8);
    STORE_C(); __syncthreads();

    // ---- P9 (B): set3 bits 4-7 + measure ----
    LOAD_B();
    GATE_BIT(0, s_U[3][9]); GATE_BIT(1, s_U[3][8]);
    GATE_BIT(2, s_U[3][7]); GATE_BIT(3, s_U[3][6]);
    EPI4(4);
    STORE_B(); __syncthreads();

    // ---- P10 (A): set3 bits 0-3 + measure (no write-back) ----
    LOAD_A();
    GATE_BIT(0, s_U[3][13]); GATE_BIT(1, s_U[3][12]);
    GATE_BIT(2, s_U[3][11]); GATE_BIT(3, s_U[3][10]);
    EPI4(0);

    // ---- block reduction ----
    #pragma unroll
    for (int off = 32; off > 0; off >>= 1)
        acc += __shfl_down(acc, off);
    if ((t & 63) == 0) s_red[t >> 6] = acc;
    __syncthreads();
    if (t == 0) {
        float s = 0.0f;
        #pragma unroll
        for (int w = 0; w < 16; ++w) s += s_red[w];
        out[n] = s;
    }
}

extern "C" void kernel_launch(void* const* d_in, const int* in_sizes, int n_in,
                              void* d_out, int out_size, void* d_ws, size_t ws_size,
                              hipStream_t stream) {
    const float* x    = (const float*)d_in[0];
    const float* psq  = (const float*)d_in[1];
    const float* p2q  = (const float*)d_in[2];
    const float* penc = (const float*)d_in[3];
    const float* pcl  = (const float*)d_in[4];
    float* out = (float*)d_out;
    pqc_kernel<<<NB, NT, 0, stream>>>(x, psq, p2q, penc, pcl, out);
}